// Round 3
// baseline (258.095 us; speedup 1.0000x reference)
//
#include <hip/hip_runtime.h>

using short8 = __attribute__((ext_vector_type(8))) short;
using f32x4  = __attribute__((ext_vector_type(4))) float;

#define HW   4800
#define MT   75            // 75 m-tiles of 64 (75*64 == 4800 exactly)
#define NPTS 1024
#define CDIM 256
#define NB   4
#define NROWS (NB*NPTS)    // 4096

// ---- workspace layout (bytes), total ~7.4 MB ----
#define OFF_BITS 0
#define SZ_BITS  (NROWS*MT*8)            // u64 exclusion bitmask per (b,n)
#define OFF_PART (OFF_BITS + SZ_BITS)
#define SZ_PART  (NB*MT*NPTS*4*4)        // per (b,mt,n): bottom-4 f32
#define OFF_INVK (OFF_PART + SZ_PART)
#define SZ_INVK  (NROWS*4)
#define OFF_POS  (OFF_INVK + SZ_INVK)
#define SZ_POS   (NROWS*4)
#define OFF_ACC  (OFF_POS + SZ_POS)      // f32 loss accumulator

__device__ inline unsigned short f2b(float v){
  unsigned int x; __builtin_memcpy(&x, &v, 4);
  x = x + 0x7fffu + ((x >> 16) & 1u);   // RNE
  return (unsigned short)(x >> 16);
}
__device__ inline int iclamp(int v, int lo, int hi){ return v < lo ? lo : (v > hi ? hi : v); }

__device__ inline void ins4(float v, float& a0, float& a1, float& a2, float& a3){
  if (v < a3){
    if (v < a2){ a3 = a2;
      if (v < a1){ a2 = a1;
        if (v < a0){ a1 = a0; a0 = v; } else a1 = v;
      } else a2 = v;
    } else a3 = v;
  }
}

// merge two sorted-ascending 4-lists across lanes (xor partner), keep lowest 4
__device__ inline void merge4(float& s0, float& s1, float& s2, float& s3, int off){
  float b0=__shfl_xor(s0,off), b1=__shfl_xor(s1,off), b2=__shfl_xor(s2,off), b3=__shfl_xor(s3,off);
  float c0=fminf(s0,b3), c1=fminf(s1,b2), c2=fminf(s2,b1), c3=fminf(s3,b0);
  float d0=fminf(c0,c2), e2=fmaxf(c0,c2), d1=fminf(c1,c3), e3=fmaxf(c1,c3);
  s0=fminf(d0,d1); s1=fmaxf(d0,d1); s2=fminf(e2,e3); s3=fmaxf(e2,e3);
}

// 4 nearest grid-cell indices (regular 8px lattice, 60x80). The 4 nearest lattice
// points always lie in the 4x4 window of 4-nearest-x x 4-nearest-y; scan order
// (m increasing) + strict < replicates the reference's lower-index tie-break.
__device__ void nearest4(float px, float py, int* out){
  float aa = px*px + py*py;
  int ic = iclamp((int)floorf(px*0.125f - 0.5f) - 1, 0, 76);
  int jc = iclamp((int)floorf(py*0.125f - 0.5f) - 1, 0, 56);
  float v0=1e30f,v1=1e30f,v2=1e30f,v3=1e30f;
  int   i0=0,i1=0,i2=0,i3=0;
  for (int jj=jc; jj<jc+4; ++jj){
    for (int ii=ic; ii<ic+4; ++ii){
      float cx = (ii+0.5f)*8.f, cy = (jj+0.5f)*8.f;
      float q = (aa + (cx*cx + cy*cy)) - 2.f*(px*cx + py*cy);
      int m = jj*80 + ii;
      if (q < v3){
        if (q < v2){ v3=v2; i3=i2;
          if (q < v1){ v2=v1; i2=i1;
            if (q < v0){ v1=v0; i1=i0; v0=q; i0=m; } else { v1=q; i1=m; }
          } else { v2=q; i2=m; }
        } else { v3=q; i3=m; }
      }
    }
  }
  out[0]=i0; out[1]=i1; out[2]=i2; out[3]=i3;
}

// One wave per (b,n): invk, bilinear-sampled pos, ids1/warp/ids2 -> exclusion bits.
__global__ __launch_bounds__(256) void prep_kernel(
    const float* kp1, const float* wkp1,
    const float* kdesc, const float* desc2,
    const float* homo,
    float* invk, float* pos, unsigned long long* bits)
{
  int wid  = blockIdx.x*4 + (threadIdx.x >> 6);
  int lane = threadIdx.x & 63;
  int b = wid >> 10;
  const float* kr = kdesc + (size_t)wid*CDIM + lane*4;
  float k0=kr[0], k1=kr[1], k2=kr[2], k3=kr[3];
  float ss = k0*k0 + k1*k1 + k2*k2 + k3*k3;
  for (int off=32; off>0; off>>=1) ss += __shfl_xor(ss, off);
  float ivk = 1.0f/sqrtf(ss + 1e-8f);

  // bilinear sample at w_kp1/8 - 0.5
  float px = wkp1[(size_t)wid*2+0]*0.125f - 0.5f;
  float py = wkp1[(size_t)wid*2+1]*0.125f - 0.5f;
  float x0f = floorf(px), y0f = floorf(py);
  float wx = px - x0f, wy = py - y0f;
  int x0 = iclamp((int)x0f, 0, 79);
  int x1 = x0+1 > 79 ? 79 : x0+1;
  int y0 = iclamp((int)y0f, 0, 59);
  int y1 = y0+1 > 59 ? 59 : y0+1;
  const float* dp = desc2 + (size_t)b*CDIM*HW;
  float wss = 0.f, wdot = 0.f;
  int cbase = lane*4;
  #pragma unroll
  for (int j=0; j<4; ++j){
    const float* p = dp + (size_t)(cbase+j)*HW;
    float d00=p[y0*80+x0], d01=p[y0*80+x1];
    float d10=p[y1*80+x0], d11=p[y1*80+x1];
    float top = d00*(1.f-wx) + d01*wx;
    float bot = d10*(1.f-wx) + d11*wx;
    float wv  = top*(1.f-wy) + bot*wy;
    wss += wv*wv;
    float kvj = (j==0) ? k0 : (j==1) ? k1 : (j==2) ? k2 : k3;
    wdot += wv*kvj;
  }
  for (int off=32; off>0; off>>=1){ wss += __shfl_xor(wss, off); wdot += __shfl_xor(wdot, off); }

  if (lane == 0){
    invk[wid] = ivk;
    float invw = 1.0f/sqrtf(wss + 1e-8f);
    pos[wid] = 2.f - 2.f*(wdot*ivk*invw);

    float qx = kp1[(size_t)wid*2+0], qy = kp1[(size_t)wid*2+1];
    int c1[4]; nearest4(qx, qy, c1);
    float h[9];
    #pragma unroll
    for (int k=0; k<9; ++k) h[k] = homo[b*9 + k];
    unsigned long long* brow = bits + (size_t)wid*MT;
    for (int t=0; t<4; ++t){
      int m = c1[t]; int ii = m % 80, jj = m / 80;
      float cx = (ii+0.5f)*8.f, cy = (jj+0.5f)*8.f;
      float wz  = h[6]*cx + h[7]*cy + h[8];
      float wxp = (h[0]*cx + h[1]*cy + h[2]) / (wz + 1e-8f);
      float wyp = (h[3]*cx + h[4]*cy + h[5]) / (wz + 1e-8f);
      int c2[4]; nearest4(wxp, wyp, c2);
      for (int u=0; u<4; ++u){
        int m2 = c2[u];
        brow[m2 >> 6] |= (1ull << (m2 & 63));
      }
    }
  }
}

// Fused: stage+transpose one 64x256 desc2 tile into LDS as bf16 MFMA fragments,
// row norms in f32, then sim^T GEMM (normalize in epilogue) with fused
// exclusion-bit skip + per-lane running bottom-4.
__global__ __launch_bounds__(256) void gemm_select(
    const float* kdesc, const float* desc2,
    const unsigned long long* bits, const float* invk, float* part)
{
  int idx = blockIdx.x;
  int b  = idx & 3;
  int r  = idx >> 2;           // 0..299
  int mt = r % MT;
  int ns = r / MT;             // 0..3: n-range [ns*256, ns*256+256)
  int t = threadIdx.x;
  int wave = t >> 6, lane = t & 63;
  int quad = lane >> 4, nl = lane & 15;

  __shared__ __align__(16) unsigned short afrag[64*256]; // ((msub*8+kf)*64 + lane)*8
  __shared__ float red[4][64];
  __shared__ float sinv[64];

  // ---- stage + transpose (f32 -> bf16) + row-ssq in f32 ----
  {
    int m_l = t & 63;
    int cq  = t >> 6;                       // c-range [cq*64, cq*64+64)
    const float* src = desc2 + (size_t)b*CDIM*HW + (size_t)mt*64 + m_l;
    int msub_s = m_l >> 4, nl_s = m_l & 15;
    float ssq = 0.f;
    for (int cb = 0; cb < 64; cb += 8){
      int c0 = cq*64 + cb;
      short8 pk;
      #pragma unroll
      for (int j = 0; j < 8; ++j){
        float f = src[(size_t)(c0+j)*HW];
        ssq += f*f;
        pk[j] = (short)f2b(f);
      }
      int kf = c0 >> 5, qd = (c0 >> 3) & 3;
      *(short8*)(afrag + (((msub_s*8 + kf)*64 + qd*16 + nl_s) << 3)) = pk;
    }
    red[cq][m_l] = ssq;
  }
  __syncthreads();
  if (t < 64) sinv[t] = 1.0f/sqrtf(red[0][t]+red[1][t]+red[2][t]+red[3][t] + 1e-8f);
  __syncthreads();

  // ---- compute: 16 n-tiles of 16, 4 per wave ----
  for (int ti = 0; ti < 4; ++ti){
    int tile = wave + ti*4;
    int n = ns*256 + tile*16 + nl;
    int row = b*NPTS + n;
    float invkn = invk[row];
    unsigned long long w64 = bits[(size_t)row*MT + mt];
    const float* kbase = kdesc + (size_t)row*CDIM + quad*8;
    short8 bf[8];
    #pragma unroll
    for (int kf=0; kf<8; ++kf){
      #pragma unroll
      for (int j=0; j<8; ++j) bf[kf][j] = (short)f2b(kbase[kf*32 + j]);
    }

    float s0=1e30f,s1=1e30f,s2=1e30f,s3=1e30f;
    #pragma unroll
    for (int msub=0; msub<4; ++msub){
      f32x4 acc = {0.f,0.f,0.f,0.f};
      #pragma unroll
      for (int kf=0; kf<8; ++kf){
        short8 a = *(short8*)(afrag + (((msub*8 + kf)*64 + lane) << 3));
        acc = __builtin_amdgcn_mfma_f32_16x16x32_bf16(a, bf[kf], acc, 0, 0, 0);
      }
      #pragma unroll
      for (int rr=0; rr<4; ++rr){
        int ml2 = msub*16 + quad*4 + rr;   // C/D layout: col=lane&15 (=n), row=quad*4+rr
        float val = 2.f - 2.f*acc[rr]*sinv[ml2]*invkn;
        if (!((w64 >> ml2) & 1ull)) ins4(val, s0,s1,s2,s3);
      }
    }
    merge4(s0,s1,s2,s3,16);
    merge4(s0,s1,s2,s3,32);
    if (lane < 16){
      f32x4 o = {s0,s1,s2,s3};
      *(f32x4*)(part + ((size_t)(b*MT + mt)*NPTS + n)*4) = o;
    }
  }
}

// One wave per (b,n): reduce bottom-4 over 75 m-tiles, hinge, block-reduce, atomic.
__global__ __launch_bounds__(1024) void finalize(const float* part, const float* pos, float* acc){
  int wave = threadIdx.x >> 6, lane = threadIdx.x & 63;
  int row = blockIdx.x*16 + wave;
  int b = row >> 10, n = row & 1023;
  float a0=1e30f, a1=1e30f, a2=1e30f, a3=1e30f;
  {
    const f32x4 v = *(const f32x4*)(part + ((size_t)(b*MT + lane)*NPTS + n)*4);
    ins4(v[0],a0,a1,a2,a3); ins4(v[1],a0,a1,a2,a3);
    ins4(v[2],a0,a1,a2,a3); ins4(v[3],a0,a1,a2,a3);
  }
  if (lane < MT-64){
    const f32x4 v = *(const f32x4*)(part + ((size_t)(b*MT + 64 + lane)*NPTS + n)*4);
    ins4(v[0],a0,a1,a2,a3); ins4(v[1],a0,a1,a2,a3);
    ins4(v[2],a0,a1,a2,a3); ins4(v[3],a0,a1,a2,a3);
  }
  #pragma unroll
  for (int off=1; off<64; off<<=1) merge4(a0,a1,a2,a3,off);

  __shared__ float ls[16];
  if (lane == 0){
    float p = pos[row];
    ls[wave] = fmaxf(p-a0+1.f,0.f) + fmaxf(p-a1+1.f,0.f)
             + fmaxf(p-a2+1.f,0.f) + fmaxf(p-a3+1.f,0.f);
  }
  __syncthreads();
  if (threadIdx.x == 0){
    float s = 0.f;
    #pragma unroll
    for (int i=0; i<16; ++i) s += ls[i];
    atomicAdd(acc, s);
  }
}

__global__ void writeout(const float* acc, float* out){
  out[0] = acc[0] * (1.0f/16384.0f);
}

extern "C" void kernel_launch(void* const* d_in, const int* in_sizes, int n_in,
                              void* d_out, int out_size, void* d_ws, size_t ws_size,
                              hipStream_t stream) {
  (void)in_sizes; (void)n_in; (void)out_size; (void)ws_size;
  const float* kp1   = (const float*)d_in[0];
  const float* wkp1  = (const float*)d_in[1];
  const float* kdesc = (const float*)d_in[2];
  const float* desc2 = (const float*)d_in[3];
  const float* homo  = (const float*)d_in[4];

  char* ws = (char*)d_ws;
  unsigned long long* bits = (unsigned long long*)(ws + OFF_BITS);
  float* part = (float*)(ws + OFF_PART);
  float* invk = (float*)(ws + OFF_INVK);
  float* pos  = (float*)(ws + OFF_POS);
  float* acc  = (float*)(ws + OFF_ACC);

  hipMemsetAsync(bits, 0, SZ_BITS, stream);
  hipMemsetAsync(acc, 0, 4, stream);

  prep_kernel<<<1024, 256, 0, stream>>>(kp1, wkp1, kdesc, desc2, homo, invk, pos, bits);
  gemm_select<<<1200, 256, 0, stream>>>(kdesc, desc2, bits, invk, part);
  finalize<<<256, 1024, 0, stream>>>(part, pos, acc);
  writeout<<<1, 1, 0, stream>>>(acc, (float*)d_out);
}

// Round 4
// 235.256 us; speedup vs baseline: 1.0971x; 1.0971x over previous
//
#include <hip/hip_runtime.h>

using short8 = __attribute__((ext_vector_type(8))) short;
using f32x4  = __attribute__((ext_vector_type(4))) float;

#define HW   4800
#define MT   75            // 75 m-tiles of 64 (75*64 == 4800 exactly)
#define NPTS 1024
#define CDIM 256
#define NB   4
#define NROWS (NB*NPTS)    // 4096

// ---- workspace layout (bytes), total ~18.4 MiB ----
#define OFF_BITS 0
#define SZ_BITS  (NROWS*MT*8)            // u64 exclusion bitmask per (b,n)
#define OFF_PART (OFF_BITS + SZ_BITS)
#define SZ_PART  (NB*MT*NPTS*4*4)        // per (b,mt,n): bottom-4 f32
#define OFF_AG   (OFF_PART + SZ_PART)
#define SZ_AG    (NB*MT*16384*2)         // fragment-ordered normalized bf16 A-tiles
#define OFF_KDN  (OFF_AG + SZ_AG)
#define SZ_KDN   (NROWS*CDIM*2)          // normalized bf16 kdesc
#define OFF_POS  (OFF_KDN + SZ_KDN)
#define SZ_POS   (NROWS*4)
#define WS_TOTAL (OFF_POS + SZ_POS)

__device__ inline unsigned short f2b(float v){
  unsigned int x; __builtin_memcpy(&x, &v, 4);
  x = x + 0x7fffu + ((x >> 16) & 1u);   // RNE
  return (unsigned short)(x >> 16);
}
__device__ inline int iclamp(int v, int lo, int hi){ return v < lo ? lo : (v > hi ? hi : v); }

__device__ inline void ins4(float v, float& a0, float& a1, float& a2, float& a3){
  if (v < a3){
    if (v < a2){ a3 = a2;
      if (v < a1){ a2 = a1;
        if (v < a0){ a1 = a0; a0 = v; } else a1 = v;
      } else a2 = v;
    } else a3 = v;
  }
}

// merge two sorted-ascending 4-lists across lanes (xor partner), keep lowest 4
__device__ inline void merge4(float& s0, float& s1, float& s2, float& s3, int off){
  float b0=__shfl_xor(s0,off), b1=__shfl_xor(s1,off), b2=__shfl_xor(s2,off), b3=__shfl_xor(s3,off);
  float c0=fminf(s0,b3), c1=fminf(s1,b2), c2=fminf(s2,b1), c3=fminf(s3,b0);
  float d0=fminf(c0,c2), e2=fmaxf(c0,c2), d1=fminf(c1,c3), e3=fmaxf(c1,c3);
  s0=fminf(d0,d1); s1=fmaxf(d0,d1); s2=fminf(e2,e3); s3=fmaxf(e2,e3);
}

// 4 nearest grid-cell indices (regular 8px lattice, 60x80).
__device__ void nearest4(float px, float py, int* out){
  float aa = px*px + py*py;
  int ic = iclamp((int)floorf(px*0.125f - 0.5f) - 1, 0, 76);
  int jc = iclamp((int)floorf(py*0.125f - 0.5f) - 1, 0, 56);
  float v0=1e30f,v1=1e30f,v2=1e30f,v3=1e30f;
  int   i0=0,i1=0,i2=0,i3=0;
  for (int jj=jc; jj<jc+4; ++jj){
    for (int ii=ic; ii<ic+4; ++ii){
      float cx = (ii+0.5f)*8.f, cy = (jj+0.5f)*8.f;
      float q = (aa + (cx*cx + cy*cy)) - 2.f*(px*cx + py*cy);
      int m = jj*80 + ii;
      if (q < v3){
        if (q < v2){ v3=v2; i3=i2;
          if (q < v1){ v2=v1; i2=i1;
            if (q < v0){ v1=v0; i1=i0; v0=q; i0=m; } else { v1=q; i1=m; }
          } else { v2=q; i2=m; }
        } else { v3=q; i3=m; }
      }
    }
  }
  out[0]=i0; out[1]=i1; out[2]=i2; out[3]=i3;
}

// One wave per (b,n): kdn (normalized bf16), pos, exclusion bits.
__global__ __launch_bounds__(256) void prep_kernel(
    const float* kp1, const float* wkp1,
    const float* kdesc, const float* desc2,
    const float* homo,
    unsigned short* kdn, float* pos, unsigned long long* bits)
{
  int wid  = blockIdx.x*4 + (threadIdx.x >> 6);
  int lane = threadIdx.x & 63;
  int b = wid >> 10;
  const float* kr = kdesc + (size_t)wid*CDIM + lane*4;
  float k0=kr[0], k1=kr[1], k2=kr[2], k3=kr[3];
  float ss = k0*k0 + k1*k1 + k2*k2 + k3*k3;
  for (int off=32; off>0; off>>=1) ss += __shfl_xor(ss, off);
  float ivk = 1.0f/sqrtf(ss + 1e-8f);
  {
    unsigned short* kw = kdn + (size_t)wid*CDIM + lane*4;
    kw[0]=f2b(k0*ivk); kw[1]=f2b(k1*ivk); kw[2]=f2b(k2*ivk); kw[3]=f2b(k3*ivk);
  }

  // bilinear sample at w_kp1/8 - 0.5
  float px = wkp1[(size_t)wid*2+0]*0.125f - 0.5f;
  float py = wkp1[(size_t)wid*2+1]*0.125f - 0.5f;
  float x0f = floorf(px), y0f = floorf(py);
  float wx = px - x0f, wy = py - y0f;
  int x0 = iclamp((int)x0f, 0, 79);
  int x1 = x0+1 > 79 ? 79 : x0+1;
  int y0 = iclamp((int)y0f, 0, 59);
  int y1 = y0+1 > 59 ? 59 : y0+1;
  const float* dp = desc2 + (size_t)b*CDIM*HW;
  float wss = 0.f, wdot = 0.f;
  int cbase = lane*4;
  #pragma unroll
  for (int j=0; j<4; ++j){
    const float* p = dp + (size_t)(cbase+j)*HW;
    float d00=p[y0*80+x0], d01=p[y0*80+x1];
    float d10=p[y1*80+x0], d11=p[y1*80+x1];
    float top = d00*(1.f-wx) + d01*wx;
    float bot = d10*(1.f-wx) + d11*wx;
    float wv  = top*(1.f-wy) + bot*wy;
    wss += wv*wv;
    float kvj = (j==0) ? k0 : (j==1) ? k1 : (j==2) ? k2 : k3;
    wdot += wv*kvj;
  }
  for (int off=32; off>0; off>>=1){ wss += __shfl_xor(wss, off); wdot += __shfl_xor(wdot, off); }

  if (lane == 0){
    float invw = 1.0f/sqrtf(wss + 1e-8f);
    pos[wid] = 2.f - 2.f*(wdot*ivk*invw);

    float qx = kp1[(size_t)wid*2+0], qy = kp1[(size_t)wid*2+1];
    int c1[4]; nearest4(qx, qy, c1);
    float h[9];
    #pragma unroll
    for (int k=0; k<9; ++k) h[k] = homo[b*9 + k];
    unsigned long long* brow = bits + (size_t)wid*MT;
    for (int t=0; t<4; ++t){
      int m = c1[t]; int ii = m % 80, jj = m / 80;
      float cx = (ii+0.5f)*8.f, cy = (jj+0.5f)*8.f;
      float wz  = h[6]*cx + h[7]*cy + h[8];
      float wxp = (h[0]*cx + h[1]*cy + h[2]) / (wz + 1e-8f);
      float wyp = (h[3]*cx + h[4]*cy + h[5]) / (wz + 1e-8f);
      int c2[4]; nearest4(wxp, wyp, c2);
      for (int u=0; u<4; ++u){
        int m2 = c2[u];
        brow[m2 >> 6] |= (1ull << (m2 & 63));
      }
    }
  }
}

// One block per (b,mt): transpose + normalize 64x256 desc2 tile into
// fragment-ordered bf16 A-tiles in global (done ONCE, not per gemm block).
__global__ __launch_bounds__(256) void d2t_kernel(const float* desc2, unsigned short* a_glob){
  int mt = blockIdx.x;
  int b  = blockIdx.y;
  int t = threadIdx.x;
  int m_l = t & 63, cq = t >> 6;
  __shared__ float raw[256*64];       // [c][m], 64 KB
  __shared__ float red[4][64];
  __shared__ float sinv[64];
  const float* src = desc2 + (size_t)b*CDIM*HW + (size_t)mt*64 + m_l;
  float ssq = 0.f;
  for (int cb=0; cb<64; ++cb){
    int c = cq*64 + cb;
    float f = src[(size_t)c*HW];
    raw[c*64 + m_l] = f;
    ssq += f*f;
  }
  red[cq][m_l] = ssq;
  __syncthreads();
  if (t < 64) sinv[t] = 1.0f/sqrtf(red[0][t]+red[1][t]+red[2][t]+red[3][t] + 1e-8f);
  __syncthreads();
  float inv = sinv[m_l];
  int msub_s = m_l >> 4, nl_s = m_l & 15;
  unsigned short* dst = a_glob + (size_t)(b*MT + mt)*16384;
  for (int cb=0; cb<64; cb+=8){
    int c0 = cq*64 + cb;
    short8 pk;
    #pragma unroll
    for (int j=0; j<8; ++j) pk[j] = (short)f2b(raw[(c0+j)*64 + m_l] * inv);
    int kf = c0 >> 5, qd = (c0 >> 3) & 3;
    *(short8*)(dst + (((msub_s*8 + kf)*64 + qd*16 + nl_s) << 3)) = pk;
  }
}

// Pure GEMM+select: coalesced short8 fragment loads, 128 MFMA/lane, no LDS.
__global__ __launch_bounds__(256) void gemm_select(
    const unsigned short* kdn, const unsigned short* a_glob,
    const unsigned long long* bits, float* part)
{
  int idx = blockIdx.x;
  int b  = idx & 3;
  int r  = idx >> 2;           // 0..299
  int mt = r % MT;
  int ns = r / MT;             // 0..3
  int t = threadIdx.x;
  int wave = t >> 6, lane = t & 63;
  int quad = lane >> 4, nl = lane & 15;
  const unsigned short* atile = a_glob + (size_t)(b*MT + mt)*16384;

  for (int ti = 0; ti < 4; ++ti){
    int tile = wave + ti*4;
    int n = ns*256 + tile*16 + nl;
    int row = b*NPTS + n;
    unsigned long long w64 = bits[(size_t)row*MT + mt];
    const unsigned short* kbase = kdn + (size_t)row*CDIM + quad*8;
    short8 bf[8];
    #pragma unroll
    for (int kf=0; kf<8; ++kf) bf[kf] = *(const short8*)(kbase + kf*32);

    float s0=1e30f,s1=1e30f,s2=1e30f,s3=1e30f;
    #pragma unroll
    for (int msub=0; msub<4; ++msub){
      f32x4 acc = {0.f,0.f,0.f,0.f};
      #pragma unroll
      for (int kf=0; kf<8; ++kf){
        short8 a = *(const short8*)(atile + (((msub*8 + kf)*64 + lane) << 3));
        acc = __builtin_amdgcn_mfma_f32_16x16x32_bf16(a, bf[kf], acc, 0, 0, 0);
      }
      #pragma unroll
      for (int rr=0; rr<4; ++rr){
        int ml2 = msub*16 + quad*4 + rr;   // C/D: col=lane&15 (=n), row=quad*4+rr
        float val = 2.f - 2.f*acc[rr];
        if (!((w64 >> ml2) & 1ull)) ins4(val, s0,s1,s2,s3);
      }
    }
    merge4(s0,s1,s2,s3,16);
    merge4(s0,s1,s2,s3,32);
    if (lane < 16){
      f32x4 o = {s0,s1,s2,s3};
      *(f32x4*)(part + ((size_t)(b*MT + mt)*NPTS + n)*4) = o;
    }
  }
}

// One wave per (b,n): reduce bottom-4 over 75 m-tiles, hinge, atomic into d_out.
__global__ __launch_bounds__(1024) void finalize(const float* part, const float* pos, float* out){
  int wave = threadIdx.x >> 6, lane = threadIdx.x & 63;
  int row = blockIdx.x*16 + wave;
  int b = row >> 10, n = row & 1023;
  float a0=1e30f, a1=1e30f, a2=1e30f, a3=1e30f;
  {
    const f32x4 v = *(const f32x4*)(part + ((size_t)(b*MT + lane)*NPTS + n)*4);
    ins4(v[0],a0,a1,a2,a3); ins4(v[1],a0,a1,a2,a3);
    ins4(v[2],a0,a1,a2,a3); ins4(v[3],a0,a1,a2,a3);
  }
  if (lane < MT-64){
    const f32x4 v = *(const f32x4*)(part + ((size_t)(b*MT + 64 + lane)*NPTS + n)*4);
    ins4(v[0],a0,a1,a2,a3); ins4(v[1],a0,a1,a2,a3);
    ins4(v[2],a0,a1,a2,a3); ins4(v[3],a0,a1,a2,a3);
  }
  #pragma unroll
  for (int off=1; off<64; off<<=1) merge4(a0,a1,a2,a3,off);

  __shared__ float ls[16];
  if (lane == 0){
    float p = pos[row];
    ls[wave] = fmaxf(p-a0+1.f,0.f) + fmaxf(p-a1+1.f,0.f)
             + fmaxf(p-a2+1.f,0.f) + fmaxf(p-a3+1.f,0.f);
  }
  __syncthreads();
  if (threadIdx.x == 0){
    float s = 0.f;
    #pragma unroll
    for (int i=0; i<16; ++i) s += ls[i];
    atomicAdd(out, s * (1.0f/16384.0f));
  }
}

__global__ void ws_too_small(float* out){ out[0] = -12345.0f; }

extern "C" void kernel_launch(void* const* d_in, const int* in_sizes, int n_in,
                              void* d_out, int out_size, void* d_ws, size_t ws_size,
                              hipStream_t stream) {
  (void)in_sizes; (void)n_in; (void)out_size;
  if (ws_size < (size_t)WS_TOTAL){
    ws_too_small<<<1, 1, 0, stream>>>((float*)d_out);
    return;
  }
  const float* kp1   = (const float*)d_in[0];
  const float* wkp1  = (const float*)d_in[1];
  const float* kdesc = (const float*)d_in[2];
  const float* desc2 = (const float*)d_in[3];
  const float* homo  = (const float*)d_in[4];

  char* ws = (char*)d_ws;
  unsigned long long* bits = (unsigned long long*)(ws + OFF_BITS);
  float*          part   = (float*)(ws + OFF_PART);
  unsigned short* a_glob = (unsigned short*)(ws + OFF_AG);
  unsigned short* kdn    = (unsigned short*)(ws + OFF_KDN);
  float*          pos    = (float*)(ws + OFF_POS);

  hipMemsetAsync(bits, 0, SZ_BITS, stream);
  hipMemsetAsync(d_out, 0, 4, stream);

  prep_kernel<<<1024, 256, 0, stream>>>(kp1, wkp1, kdesc, desc2, homo, kdn, pos, bits);
  d2t_kernel<<<dim3(MT, NB), 256, 0, stream>>>(desc2, a_glob);
  gemm_select<<<1200, 256, 0, stream>>>(kdn, a_glob, bits, part);
  finalize<<<256, 1024, 0, stream>>>(part, pos, (float*)d_out);
}

// Round 5
// 220.000 us; speedup vs baseline: 1.1732x; 1.0693x over previous
//
#include <hip/hip_runtime.h>

using short8 = __attribute__((ext_vector_type(8))) short;
using f32x4  = __attribute__((ext_vector_type(4))) float;

#define HW   4800
#define MT   75            // 75 m-tiles of 64 (75*64 == 4800 exactly)
#define NPTS 1024
#define CDIM 256
#define NB   4
#define NROWS (NB*NPTS)    // 4096

// ---- workspace layout (bytes), total ~18.4 MiB ----
#define OFF_BITS 0
#define SZ_BITS  (NROWS*MT*8)            // u64 exclusion bitmask per (b,n)
#define OFF_PART (OFF_BITS + SZ_BITS)
#define SZ_PART  (NB*MT*NPTS*4*4)        // per (b,mt,n): bottom-4 f32
#define OFF_AG   (OFF_PART + SZ_PART)
#define SZ_AG    (NB*MT*16384*2)         // fragment-ordered normalized bf16 A-tiles
#define OFF_KDN  (OFF_AG + SZ_AG)
#define SZ_KDN   (NROWS*CDIM*2)          // normalized bf16 kdesc
#define OFF_POS  (OFF_KDN + SZ_KDN)
#define SZ_POS   (NROWS*4)
#define WS_TOTAL (OFF_POS + SZ_POS)

__device__ inline unsigned short f2b(float v){
  unsigned int x; __builtin_memcpy(&x, &v, 4);
  x = x + 0x7fffu + ((x >> 16) & 1u);   // RNE
  return (unsigned short)(x >> 16);
}
__device__ inline int iclamp(int v, int lo, int hi){ return v < lo ? lo : (v > hi ? hi : v); }

__device__ inline void ins4(float v, float& a0, float& a1, float& a2, float& a3){
  if (v < a3){
    if (v < a2){ a3 = a2;
      if (v < a1){ a2 = a1;
        if (v < a0){ a1 = a0; a0 = v; } else a1 = v;
      } else a2 = v;
    } else a3 = v;
  }
}

// merge two sorted-ascending 4-lists across lanes (xor partner), keep lowest 4
__device__ inline void merge4(float& s0, float& s1, float& s2, float& s3, int off){
  float b0=__shfl_xor(s0,off), b1=__shfl_xor(s1,off), b2=__shfl_xor(s2,off), b3=__shfl_xor(s3,off);
  float c0=fminf(s0,b3), c1=fminf(s1,b2), c2=fminf(s2,b1), c3=fminf(s3,b0);
  float d0=fminf(c0,c2), e2=fmaxf(c0,c2), d1=fminf(c1,c3), e3=fmaxf(c1,c3);
  s0=fminf(d0,d1); s1=fmaxf(d0,d1); s2=fminf(e2,e3); s3=fmaxf(e2,e3);
}

// 4 nearest grid-cell indices (regular 8px lattice, 60x80).
__device__ void nearest4(float px, float py, int* out){
  float aa = px*px + py*py;
  int ic = iclamp((int)floorf(px*0.125f - 0.5f) - 1, 0, 76);
  int jc = iclamp((int)floorf(py*0.125f - 0.5f) - 1, 0, 56);
  float v0=1e30f,v1=1e30f,v2=1e30f,v3=1e30f;
  int   i0=0,i1=0,i2=0,i3=0;
  for (int jj=jc; jj<jc+4; ++jj){
    for (int ii=ic; ii<ic+4; ++ii){
      float cx = (ii+0.5f)*8.f, cy = (jj+0.5f)*8.f;
      float q = (aa + (cx*cx + cy*cy)) - 2.f*(px*cx + py*cy);
      int m = jj*80 + ii;
      if (q < v3){
        if (q < v2){ v3=v2; i3=i2;
          if (q < v1){ v2=v1; i2=i1;
            if (q < v0){ v1=v0; i1=i0; v0=q; i0=m; } else { v1=q; i1=m; }
          } else { v2=q; i2=m; }
        } else { v3=q; i3=m; }
      }
    }
  }
  out[0]=i0; out[1]=i1; out[2]=i2; out[3]=i3;
}

// One wave per (b,n): kdn (normalized bf16), pos, exclusion bits.
__global__ __launch_bounds__(256) void prep_kernel(
    const float* kp1, const float* wkp1,
    const float* kdesc, const float* desc2,
    const float* homo,
    unsigned short* kdn, float* pos, unsigned long long* bits)
{
  int wid  = blockIdx.x*4 + (threadIdx.x >> 6);
  int lane = threadIdx.x & 63;
  int b = wid >> 10;
  const float* kr = kdesc + (size_t)wid*CDIM + lane*4;
  float k0=kr[0], k1=kr[1], k2=kr[2], k3=kr[3];
  float ss = k0*k0 + k1*k1 + k2*k2 + k3*k3;
  for (int off=32; off>0; off>>=1) ss += __shfl_xor(ss, off);
  float ivk = 1.0f/sqrtf(ss + 1e-8f);
  {
    unsigned short* kw = kdn + (size_t)wid*CDIM + lane*4;
    kw[0]=f2b(k0*ivk); kw[1]=f2b(k1*ivk); kw[2]=f2b(k2*ivk); kw[3]=f2b(k3*ivk);
  }

  // bilinear sample at w_kp1/8 - 0.5
  float px = wkp1[(size_t)wid*2+0]*0.125f - 0.5f;
  float py = wkp1[(size_t)wid*2+1]*0.125f - 0.5f;
  float x0f = floorf(px), y0f = floorf(py);
  float wx = px - x0f, wy = py - y0f;
  int x0 = iclamp((int)x0f, 0, 79);
  int x1 = x0+1 > 79 ? 79 : x0+1;
  int y0 = iclamp((int)y0f, 0, 59);
  int y1 = y0+1 > 59 ? 59 : y0+1;
  const float* dp = desc2 + (size_t)b*CDIM*HW;
  float wss = 0.f, wdot = 0.f;
  int cbase = lane*4;
  #pragma unroll
  for (int j=0; j<4; ++j){
    const float* p = dp + (size_t)(cbase+j)*HW;
    float d00=p[y0*80+x0], d01=p[y0*80+x1];
    float d10=p[y1*80+x0], d11=p[y1*80+x1];
    float top = d00*(1.f-wx) + d01*wx;
    float bot = d10*(1.f-wx) + d11*wx;
    float wv  = top*(1.f-wy) + bot*wy;
    wss += wv*wv;
    float kvj = (j==0) ? k0 : (j==1) ? k1 : (j==2) ? k2 : k3;
    wdot += wv*kvj;
  }
  for (int off=32; off>0; off>>=1){ wss += __shfl_xor(wss, off); wdot += __shfl_xor(wdot, off); }

  if (lane == 0){
    float invw = 1.0f/sqrtf(wss + 1e-8f);
    pos[wid] = 2.f - 2.f*(wdot*ivk*invw);

    float qx = kp1[(size_t)wid*2+0], qy = kp1[(size_t)wid*2+1];
    int c1[4]; nearest4(qx, qy, c1);
    float h[9];
    #pragma unroll
    for (int k=0; k<9; ++k) h[k] = homo[b*9 + k];
    unsigned long long* brow = bits + (size_t)wid*MT;
    for (int t=0; t<4; ++t){
      int m = c1[t]; int ii = m % 80, jj = m / 80;
      float cx = (ii+0.5f)*8.f, cy = (jj+0.5f)*8.f;
      float wz  = h[6]*cx + h[7]*cy + h[8];
      float wxp = (h[0]*cx + h[1]*cy + h[2]) / (wz + 1e-8f);
      float wyp = (h[3]*cx + h[4]*cy + h[5]) / (wz + 1e-8f);
      int c2[4]; nearest4(wxp, wyp, c2);
      for (int u=0; u<4; ++u){
        int m2 = c2[u];
        brow[m2 >> 6] |= (1ull << (m2 & 63));
      }
    }
  }
}

// One block per (b,mt): transpose + normalize 64x256 desc2 tile into
// fragment-ordered bf16 A-tiles in global (done once).
__global__ __launch_bounds__(256) void d2t_kernel(const float* desc2, unsigned short* a_glob){
  int mt = blockIdx.x;
  int b  = blockIdx.y;
  int t = threadIdx.x;
  int m_l = t & 63, cq = t >> 6;
  __shared__ float raw[256*64];       // [c][m], 64 KB
  __shared__ float red[4][64];
  __shared__ float sinv[64];
  const float* src = desc2 + (size_t)b*CDIM*HW + (size_t)mt*64 + m_l;
  float ssq = 0.f;
  for (int cb=0; cb<64; ++cb){
    int c = cq*64 + cb;
    float f = src[(size_t)c*HW];
    raw[c*64 + m_l] = f;
    ssq += f*f;
  }
  red[cq][m_l] = ssq;
  __syncthreads();
  if (t < 64) sinv[t] = 1.0f/sqrtf(red[0][t]+red[1][t]+red[2][t]+red[3][t] + 1e-8f);
  __syncthreads();
  float inv = sinv[m_l];
  int msub_s = m_l >> 4, nl_s = m_l & 15;
  unsigned short* dst = a_glob + (size_t)(b*MT + mt)*16384;
  for (int cb=0; cb<64; cb+=8){
    int c0 = cq*64 + cb;
    short8 pk;
    #pragma unroll
    for (int j=0; j<8; ++j) pk[j] = (short)f2b(raw[(c0+j)*64 + m_l] * inv);
    int kf = c0 >> 5, qd = (c0 >> 3) & 3;
    *(short8*)(dst + (((msub_s*8 + kf)*64 + qd*16 + nl_s) << 3)) = pk;
  }
}

// Pure GEMM+select. Grid: 4800 blocks = (b, mt, ns16); wave = one 16-n tile.
// 8 independent 4-MFMA chains per wave for ILP; no LDS, no syncthreads.
__global__ __launch_bounds__(256) void gemm_select(
    const unsigned short* kdn, const unsigned short* a_glob,
    const unsigned long long* bits, float* part)
{
  int idx = blockIdx.x;
  int b  = idx & 3;
  int r  = idx >> 2;           // 0..1199
  int mt = r % MT;
  int ns = r / MT;             // 0..15: n-range [ns*64, ns*64+64)
  int t = threadIdx.x;
  int wave = t >> 6, lane = t & 63;
  int quad = lane >> 4, nl = lane & 15;
  const unsigned short* atile = a_glob + (size_t)(b*MT + mt)*16384;

  int n = ns*64 + wave*16 + nl;
  int row = b*NPTS + n;
  unsigned long long w64 = bits[(size_t)row*MT + mt];
  const unsigned short* kbase = kdn + (size_t)row*CDIM + quad*8;
  short8 bf[8];
  #pragma unroll
  for (int kf=0; kf<8; ++kf) bf[kf] = *(const short8*)(kbase + kf*32);

  float s0=1e30f,s1=1e30f,s2=1e30f,s3=1e30f;
  #pragma unroll
  for (int msub=0; msub<4; ++msub){
    const unsigned short* abase = atile + ((msub*8*64 + lane) << 3);
    f32x4 accA = {0.f,0.f,0.f,0.f}, accB = {0.f,0.f,0.f,0.f};
    #pragma unroll
    for (int kf=0; kf<4; ++kf){
      short8 aA = *(const short8*)(abase + ((kf*64) << 3));
      short8 aB = *(const short8*)(abase + (((kf+4)*64) << 3));
      accA = __builtin_amdgcn_mfma_f32_16x16x32_bf16(aA, bf[kf],   accA, 0, 0, 0);
      accB = __builtin_amdgcn_mfma_f32_16x16x32_bf16(aB, bf[kf+4], accB, 0, 0, 0);
    }
    #pragma unroll
    for (int rr=0; rr<4; ++rr){
      int ml2 = msub*16 + quad*4 + rr;   // C/D: col=lane&15 (=n), row=quad*4+rr
      float val = 2.f - 2.f*(accA[rr] + accB[rr]);
      if (!((w64 >> ml2) & 1ull)) ins4(val, s0,s1,s2,s3);
    }
  }
  merge4(s0,s1,s2,s3,16);
  merge4(s0,s1,s2,s3,32);
  if (lane < 16){
    f32x4 o = {s0,s1,s2,s3};
    *(f32x4*)(part + ((size_t)(b*MT + mt)*NPTS + n)*4) = o;
  }
}

// One wave per (b,n): reduce bottom-4 over 75 m-tiles, hinge, atomic into d_out.
__global__ __launch_bounds__(1024) void finalize(const float* part, const float* pos, float* out){
  int wave = threadIdx.x >> 6, lane = threadIdx.x & 63;
  int row = blockIdx.x*16 + wave;
  int b = row >> 10, n = row & 1023;
  float a0=1e30f, a1=1e30f, a2=1e30f, a3=1e30f;
  {
    const f32x4 v = *(const f32x4*)(part + ((size_t)(b*MT + lane)*NPTS + n)*4);
    ins4(v[0],a0,a1,a2,a3); ins4(v[1],a0,a1,a2,a3);
    ins4(v[2],a0,a1,a2,a3); ins4(v[3],a0,a1,a2,a3);
  }
  if (lane < MT-64){
    const f32x4 v = *(const f32x4*)(part + ((size_t)(b*MT + 64 + lane)*NPTS + n)*4);
    ins4(v[0],a0,a1,a2,a3); ins4(v[1],a0,a1,a2,a3);
    ins4(v[2],a0,a1,a2,a3); ins4(v[3],a0,a1,a2,a3);
  }
  #pragma unroll
  for (int off=1; off<64; off<<=1) merge4(a0,a1,a2,a3,off);

  __shared__ float ls[16];
  if (lane == 0){
    float p = pos[row];
    ls[wave] = fmaxf(p-a0+1.f,0.f) + fmaxf(p-a1+1.f,0.f)
             + fmaxf(p-a2+1.f,0.f) + fmaxf(p-a3+1.f,0.f);
  }
  __syncthreads();
  if (threadIdx.x == 0){
    float s = 0.f;
    #pragma unroll
    for (int i=0; i<16; ++i) s += ls[i];
    atomicAdd(out, s * (1.0f/16384.0f));
  }
}

__global__ void ws_too_small(float* out){ out[0] = -12345.0f; }

extern "C" void kernel_launch(void* const* d_in, const int* in_sizes, int n_in,
                              void* d_out, int out_size, void* d_ws, size_t ws_size,
                              hipStream_t stream) {
  (void)in_sizes; (void)n_in; (void)out_size;
  if (ws_size < (size_t)WS_TOTAL){
    ws_too_small<<<1, 1, 0, stream>>>((float*)d_out);
    return;
  }
  const float* kp1   = (const float*)d_in[0];
  const float* wkp1  = (const float*)d_in[1];
  const float* kdesc = (const float*)d_in[2];
  const float* desc2 = (const float*)d_in[3];
  const float* homo  = (const float*)d_in[4];

  char* ws = (char*)d_ws;
  unsigned long long* bits = (unsigned long long*)(ws + OFF_BITS);
  float*          part   = (float*)(ws + OFF_PART);
  unsigned short* a_glob = (unsigned short*)(ws + OFF_AG);
  unsigned short* kdn    = (unsigned short*)(ws + OFF_KDN);
  float*          pos    = (float*)(ws + OFF_POS);

  hipMemsetAsync(bits, 0, SZ_BITS, stream);
  hipMemsetAsync(d_out, 0, 4, stream);

  prep_kernel<<<1024, 256, 0, stream>>>(kp1, wkp1, kdesc, desc2, homo, kdn, pos, bits);
  d2t_kernel<<<dim3(MT, NB), 256, 0, stream>>>(desc2, a_glob);
  gemm_select<<<4800, 256, 0, stream>>>(kdn, a_glob, bits, part);
  finalize<<<256, 1024, 0, stream>>>(part, pos, (float*)d_out);
}